// Round 1
// baseline (633.482 us; speedup 1.0000x reference)
//
#include <hip/hip_runtime.h>

namespace {
constexpr int NB   = 256;   // batches
constexpr int NN   = 1024;  // elements per batch
constexpr int DIN  = 64;
constexpr int HID  = 256;
constexpr int DOUT = 128;
constexpr int MT   = 32;    // element rows per phi tile
constexpr int PAD  = 36;    // padded minor dim of transposed LDS tiles (keeps float4 align, breaks conflicts)

__launch_bounds__(256, 1)
__global__ void deepset_fused(const float* __restrict__ x,
                              const int*   __restrict__ mask,
                              const float* __restrict__ pw1, const float* __restrict__ pb1,
                              const float* __restrict__ pw2, const float* __restrict__ pb2,
                              const float* __restrict__ pw3, const float* __restrict__ pb3,
                              const float* __restrict__ rw1, const float* __restrict__ rb1,
                              const float* __restrict__ rw2, const float* __restrict__ rb2,
                              const float* __restrict__ rw3, const float* __restrict__ rb3,
                              float* __restrict__ out)
{
    __shared__ float xs[DIN][PAD];     // x tile, transposed: xs[k][row]       (9.2 KB)
    __shared__ float h1s[HID][PAD];    // h1 tile, transposed: h1s[col][row]   (36.9 KB)
    __shared__ float pools[8][HID];    // per-row-group pooled partials        (8 KB)
    __shared__ short vlist[NN];        // compacted valid n indices            (2 KB)
    __shared__ int   cnt_s;

    const int b      = blockIdx.x;
    const int t      = threadIdx.x;
    const int lane31 = t & 31;         // column phase: thread owns cols {lane31 + 32*j}
    const int trow   = t >> 5;         // row group 0..7
    const int r0     = trow * 4;       // rows r0..r0+3

    // ---- compact valid element indices (order irrelevant: sum-pool) ----
    if (t == 0) cnt_s = 0;
    __syncthreads();
    for (int n = t; n < NN; n += 256) {
        if (mask[b * NN + n] != 0) {
            int idx = atomicAdd(&cnt_s, 1);
            vlist[idx] = (short)n;
        }
    }
    __syncthreads();
    const int cnt = cnt_s;

    float pool[8];
#pragma unroll
    for (int j = 0; j < 8; ++j) pool[j] = 0.f;

    const float* xb = x + (size_t)b * NN * DIN;

    for (int base = 0; base < cnt; base += MT) {
        const int rows = min(MT, cnt - base);

        // ---- gather x rows for this tile -> registers ----
        const int gi = t >> 3;           // row in tile 0..31
        const int gd = (t & 7) * 8;      // feature start
        float4 v0 = make_float4(0.f, 0.f, 0.f, 0.f), v1 = v0;
        if (gi < rows) {
            const float* src = xb + (size_t)vlist[base + gi] * DIN + gd;
            v0 = *(const float4*)(src);
            v1 = *(const float4*)(src + 4);
        }
        __syncthreads();                 // all prior-tile xs/h1s reads complete
        xs[gd + 0][gi] = v0.x; xs[gd + 1][gi] = v0.y;
        xs[gd + 2][gi] = v0.z; xs[gd + 3][gi] = v0.w;
        xs[gd + 4][gi] = v1.x; xs[gd + 5][gi] = v1.y;
        xs[gd + 6][gi] = v1.z; xs[gd + 7][gi] = v1.w;
        __syncthreads();

        // ---- layer 1: h1 = relu(x @ pw1 + pb1), tile [32 x 256] ----
        float acc[4][8];
#pragma unroll
        for (int j = 0; j < 8; ++j) {
            float bias = pb1[lane31 + 32 * j];
#pragma unroll
            for (int r = 0; r < 4; ++r) acc[r][j] = bias;
        }
#pragma unroll 4
        for (int k = 0; k < DIN; ++k) {
            float4 a = *(const float4*)&xs[k][r0];
            const float* wrow = pw1 + k * HID + lane31;
#pragma unroll
            for (int j = 0; j < 8; ++j) {
                float w = wrow[32 * j];
                acc[0][j] = fmaf(a.x, w, acc[0][j]);
                acc[1][j] = fmaf(a.y, w, acc[1][j]);
                acc[2][j] = fmaf(a.z, w, acc[2][j]);
                acc[3][j] = fmaf(a.w, w, acc[3][j]);
            }
        }
#pragma unroll
        for (int j = 0; j < 8; ++j) {
            int c = lane31 + 32 * j;
#pragma unroll
            for (int r = 0; r < 4; ++r)
                h1s[c][r0 + r] = fmaxf(acc[r][j], 0.f);
        }
        __syncthreads();

        // ---- layer 2: h2 = relu(h1 @ pw2 + pb2), pooled in registers ----
#pragma unroll
        for (int j = 0; j < 8; ++j) {
            float bias = pb2[lane31 + 32 * j];
#pragma unroll
            for (int r = 0; r < 4; ++r) acc[r][j] = bias;
        }
#pragma unroll 2
        for (int k = 0; k < HID; ++k) {
            float4 a = *(const float4*)&h1s[k][r0];
            const float* wrow = pw2 + k * HID + lane31;
#pragma unroll
            for (int j = 0; j < 8; ++j) {
                float w = wrow[32 * j];
                acc[0][j] = fmaf(a.x, w, acc[0][j]);
                acc[1][j] = fmaf(a.y, w, acc[1][j]);
                acc[2][j] = fmaf(a.z, w, acc[2][j]);
                acc[3][j] = fmaf(a.w, w, acc[3][j]);
            }
        }
#pragma unroll
        for (int r = 0; r < 4; ++r) {
            if (base + r0 + r < cnt) {
#pragma unroll
                for (int j = 0; j < 8; ++j)
                    pool[j] += fmaxf(acc[r][j], 0.f);
            }
        }
    }

    // ---- reduce pooled partials across the 8 row groups ----
#pragma unroll
    for (int j = 0; j < 8; ++j)
        pools[trow][lane31 + 32 * j] = pool[j];
    __syncthreads();
    float p2 = 0.f;
#pragma unroll
    for (int g = 0; g < 8; ++g) p2 += pools[g][t];

    float* bufA = &xs[0][0];    // reuse LDS as 256-float layer buffers
    float* bufB = &h1s[0][0];

    bufA[t] = p2;
    __syncthreads();

    // ---- folded third phi layer: p3 = pooled2 @ pw3 + cnt * pb3 ----
    float a3 = (float)cnt * pb3[t];
    for (int k = 0; k < HID; ++k)
        a3 = fmaf(bufA[k], pw3[k * HID + t], a3);
    bufB[t] = a3;
    __syncthreads();

    // ---- rho layer 1 ----
    float o1 = rb1[t];
    for (int k = 0; k < HID; ++k)
        o1 = fmaf(bufB[k], rw1[k * HID + t], o1);
    o1 = fmaxf(o1, 0.f);
    bufA[t] = o1;
    __syncthreads();

    // ---- rho layer 2 ----
    float o2 = rb2[t];
    for (int k = 0; k < HID; ++k)
        o2 = fmaf(bufA[k], rw2[k * HID + t], o2);
    o2 = fmaxf(o2, 0.f);
    bufB[t] = o2;
    __syncthreads();

    // ---- rho layer 3 + zero-row gating ----
    if (t < DOUT) {
        float o3 = rb3[t];
        for (int k = 0; k < HID; ++k)
            o3 = fmaf(bufB[k], rw3[k * DOUT + t], o3);
        out[b * DOUT + t] = (cnt > 0) ? o3 : 0.f;
    }
}
} // namespace

extern "C" void kernel_launch(void* const* d_in, const int* in_sizes, int n_in,
                              void* d_out, int out_size, void* d_ws, size_t ws_size,
                              hipStream_t stream) {
    const float* x    = (const float*)d_in[0];
    const int*   mask = (const int*)  d_in[1];
    const float* pw1  = (const float*)d_in[2];
    const float* pb1  = (const float*)d_in[3];
    const float* pw2  = (const float*)d_in[4];
    const float* pb2  = (const float*)d_in[5];
    const float* pw3  = (const float*)d_in[6];
    const float* pb3  = (const float*)d_in[7];
    const float* rw1  = (const float*)d_in[8];
    const float* rb1  = (const float*)d_in[9];
    const float* rw2  = (const float*)d_in[10];
    const float* rb2  = (const float*)d_in[11];
    const float* rw3  = (const float*)d_in[12];
    const float* rb3  = (const float*)d_in[13];
    float* out = (float*)d_out;

    deepset_fused<<<dim3(NB), dim3(256), 0, stream>>>(
        x, mask, pw1, pb1, pw2, pb2, pw3, pb3,
        rw1, rb1, rw2, rb2, rw3, rb3, out);
}

// Round 2
// 187.977 us; speedup vs baseline: 3.3700x; 3.3700x over previous
//
#include <hip/hip_runtime.h>

namespace {
constexpr int NB = 256, NN = 1024, DIN = 64, HID = 256, DOUT = 128;
constexpr int SPLIT = 4;
constexpr int CHUNK = NN / SPLIT;     // 256 elements per block
constexpr int MT = 64;                // rows per phi tile
constexpr int XPAD = 72;              // xs row stride (bf16 elems) -> 144B, 16B-aligned, 2-way banks
constexpr int HPAD = 264;             // h1s row stride (bf16 elems) -> 528B, 16B-aligned, 2-way banks

typedef __attribute__((ext_vector_type(8))) short bf16x8;
typedef __attribute__((ext_vector_type(4))) float f32x4;

// ws layout
constexpr size_t POOLED_OFF = 0;                                   // NB*HID fp32 = 256KB
constexpr size_t PW1_OFF = (size_t)NB * HID * 4;                   // DIN*HID bf16 = 32KB
constexpr size_t PW2_OFF = PW1_OFF + (size_t)DIN * HID * 2;        // HID*HID bf16 = 128KB

__device__ inline unsigned short f2bf(float f) {   // RNE float->bf16
    union { float f; unsigned u; } v; v.f = f;
    unsigned r = v.u + 0x7FFF + ((v.u >> 16) & 1);
    return (unsigned short)(r >> 16);
}

// ---- kernel 0: zero pooled + pack weights into MFMA B-fragment order ----
// B-frag for 16x16x32: lane holds W[k0 + (lane>>4)*8 + j][n0 + (lane&15)], j=0..7 contiguous.
__global__ void prep(const float* __restrict__ pw1, const float* __restrict__ pw2,
                     float* __restrict__ pooled,
                     unsigned short* __restrict__ w1p, unsigned short* __restrict__ w2p) {
    int i = blockIdx.x * 256 + threadIdx.x;           // grid covers 65536
    if (i < NB * HID) pooled[i] = 0.f;
    if (i < DIN * HID) {                               // W1: KS=2, strips=16
        int j = i & 7, lane = (i >> 3) & 63, kk = (i >> 9) & 1, s = i >> 10;
        int n = s * 16 + (lane & 15);
        int k = kk * 32 + ((lane >> 4) * 8) + j;
        w1p[i] = f2bf(pw1[k * HID + n]);
    }
    if (i < HID * HID) {                               // W2: KS=8, strips=16
        int j = i & 7, lane = (i >> 3) & 63, kk = (i >> 9) & 7, s = i >> 12;
        int n = s * 16 + (lane & 15);
        int k = kk * 32 + ((lane >> 4) * 8) + j;
        w2p[i] = f2bf(pw2[k * HID + n]);
    }
}

// ---- kernel 1: phi (2 bf16 MFMA layers) + masked pool, atomics into pooled ----
__launch_bounds__(256, 2)
__global__ void phi_pool(const float* __restrict__ x, const int* __restrict__ mask,
                         const float* __restrict__ pb1, const float* __restrict__ pb2,
                         const unsigned short* __restrict__ w1p,
                         const unsigned short* __restrict__ w2p,
                         float* __restrict__ pooled) {
    __shared__ unsigned short xs[MT * XPAD];    // x tile bf16 [row][64(+8)]
    __shared__ unsigned short h1s[MT * HPAD];   // h1 tile bf16 [row][256(+8)]
    __shared__ short vlist[CHUNK];
    __shared__ int cnt_s;

    const int b = blockIdx.x, sp = blockIdx.y;
    const int t = threadIdx.x;
    const int lane = t & 63, wid = t >> 6;
    const int quad = lane >> 4, l15 = lane & 15;
    const int half = wid & 1;          // cols half*128
    const int slab = wid >> 1;         // rows slab*32

    if (t == 0) cnt_s = 0;
    __syncthreads();
    {
        int n = sp * CHUNK + t;
        if (mask[b * NN + n] != 0) { int idx = atomicAdd(&cnt_s, 1); vlist[idx] = (short)n; }
    }
    __syncthreads();
    const int cnt = cnt_s;

    float bias1[8], bias2[8];
#pragma unroll
    for (int j = 0; j < 8; ++j) {
        int c = half * 128 + j * 16 + l15;
        bias1[j] = pb1[c]; bias2[j] = pb2[c];
    }

    float pool[8];
#pragma unroll
    for (int j = 0; j < 8; ++j) pool[j] = 0.f;

    const float* xb = x + (size_t)b * NN * DIN;
    const uint4* w1q = (const uint4*)w1p;
    const uint4* w2q = (const uint4*)w2p;

    for (int base = 0; base < cnt; base += MT) {
        const int rows = min(MT, cnt - base);
        __syncthreads();  // prior-tile xs/h1s readers done

        // ---- gather x rows -> bf16 LDS tile ----
        {
            int r = t >> 2, c0 = (t & 3) * 16;
            float fv[16];
#pragma unroll
            for (int i = 0; i < 16; ++i) fv[i] = 0.f;
            if (r < rows) {
                const float* src = xb + (size_t)vlist[base + r] * DIN + c0;
                const float4* s4 = (const float4*)src;
                float4 a = s4[0], bq = s4[1], cq = s4[2], dq = s4[3];
                fv[0]=a.x; fv[1]=a.y; fv[2]=a.z; fv[3]=a.w;
                fv[4]=bq.x; fv[5]=bq.y; fv[6]=bq.z; fv[7]=bq.w;
                fv[8]=cq.x; fv[9]=cq.y; fv[10]=cq.z; fv[11]=cq.w;
                fv[12]=dq.x; fv[13]=dq.y; fv[14]=dq.z; fv[15]=dq.w;
            }
            unsigned short tmp[16];
#pragma unroll
            for (int i = 0; i < 16; ++i) tmp[i] = f2bf(fv[i]);
            uint4* dst = (uint4*)&xs[r * XPAD + c0];
            dst[0] = ((const uint4*)tmp)[0];
            dst[1] = ((const uint4*)tmp)[1];
        }
        __syncthreads();

        // ---- layer 1: h1 = relu(x @ W1 + b1); wave tile 32 rows x 128 cols ----
        f32x4 acc1[2][8];
#pragma unroll
        for (int f = 0; f < 2; ++f)
#pragma unroll
            for (int j = 0; j < 8; ++j) acc1[f][j] = (f32x4){0.f, 0.f, 0.f, 0.f};

#pragma unroll
        for (int kk = 0; kk < 2; ++kk) {
            bf16x8 a0 = *(const bf16x8*)&xs[(slab * 32 + l15) * XPAD + kk * 32 + quad * 8];
            bf16x8 a1 = *(const bf16x8*)&xs[(slab * 32 + 16 + l15) * XPAD + kk * 32 + quad * 8];
#pragma unroll
            for (int j = 0; j < 8; ++j) {
                bf16x8 bf = __builtin_bit_cast(bf16x8, w1q[((half * 8 + j) * 2 + kk) * 64 + lane]);
                acc1[0][j] = __builtin_amdgcn_mfma_f32_16x16x32_bf16(a0, bf, acc1[0][j], 0, 0, 0);
                acc1[1][j] = __builtin_amdgcn_mfma_f32_16x16x32_bf16(a1, bf, acc1[1][j], 0, 0, 0);
            }
        }
        // epilogue: bias+relu -> bf16 -> h1s (C layout: row=quad*4+reg, col=lane&15)
#pragma unroll
        for (int f = 0; f < 2; ++f)
#pragma unroll
            for (int j = 0; j < 8; ++j)
#pragma unroll
                for (int r = 0; r < 4; ++r) {
                    float h = fmaxf(acc1[f][j][r] + bias1[j], 0.f);
                    int row = slab * 32 + f * 16 + quad * 4 + r;
                    int col = half * 128 + j * 16 + l15;
                    h1s[row * HPAD + col] = f2bf(h);
                }
        __syncthreads();

        // ---- layer 2: h2 = relu(h1 @ W2 + b2), pooled in registers ----
        f32x4 acc2[2][8];
#pragma unroll
        for (int f = 0; f < 2; ++f)
#pragma unroll
            for (int j = 0; j < 8; ++j) acc2[f][j] = (f32x4){0.f, 0.f, 0.f, 0.f};

#pragma unroll 2
        for (int kk = 0; kk < 8; ++kk) {
            bf16x8 a0 = *(const bf16x8*)&h1s[(slab * 32 + l15) * HPAD + kk * 32 + quad * 8];
            bf16x8 a1 = *(const bf16x8*)&h1s[(slab * 32 + 16 + l15) * HPAD + kk * 32 + quad * 8];
#pragma unroll
            for (int j = 0; j < 8; ++j) {
                bf16x8 bf = __builtin_bit_cast(bf16x8, w2q[((half * 8 + j) * 8 + kk) * 64 + lane]);
                acc2[0][j] = __builtin_amdgcn_mfma_f32_16x16x32_bf16(a0, bf, acc2[0][j], 0, 0, 0);
                acc2[1][j] = __builtin_amdgcn_mfma_f32_16x16x32_bf16(a1, bf, acc2[1][j], 0, 0, 0);
            }
        }
        // predicated relu+pool
#pragma unroll
        for (int f = 0; f < 2; ++f)
#pragma unroll
            for (int r = 0; r < 4; ++r) {
                int lrow = slab * 32 + f * 16 + quad * 4 + r;
                bool v = lrow < rows;
#pragma unroll
                for (int j = 0; j < 8; ++j) {
                    float h = fmaxf(acc2[f][j][r] + bias2[j], 0.f);
                    pool[j] += v ? h : 0.f;
                }
            }
    }

    // quad-reduce (lanes sharing lane&15) then one atomic per col
#pragma unroll
    for (int j = 0; j < 8; ++j) {
        float v = pool[j];
        v += __shfl_xor(v, 16, 64);
        v += __shfl_xor(v, 32, 64);
        if (quad == 0) atomicAdd(&pooled[b * HID + half * 128 + j * 16 + l15], v);
    }
}

// ---- kernel 2: folded pw3 + rho chain, fp32 ----
__launch_bounds__(256, 2)
__global__ void rho(const float* __restrict__ pooled, const int* __restrict__ mask,
                    const float* __restrict__ pw3, const float* __restrict__ pb3,
                    const float* __restrict__ rw1, const float* __restrict__ rb1,
                    const float* __restrict__ rw2, const float* __restrict__ rb2,
                    const float* __restrict__ rw3, const float* __restrict__ rb3,
                    float* __restrict__ out) {
    __shared__ float bufA[HID], bufB[HID];
    __shared__ int cnt_s;
    const int b = blockIdx.x, t = threadIdx.x;
    if (t == 0) cnt_s = 0;
    __syncthreads();
    int c = 0;
    for (int n = t; n < NN; n += 256) c += (mask[b * NN + n] != 0);
#pragma unroll
    for (int d = 1; d < 64; d <<= 1) c += __shfl_xor(c, d, 64);
    if ((t & 63) == 0) atomicAdd(&cnt_s, c);
    bufA[t] = pooled[b * HID + t];
    __syncthreads();
    const int cnt = cnt_s;

    float a3 = (float)cnt * pb3[t];
    for (int k = 0; k < HID; ++k) a3 = fmaf(bufA[k], pw3[k * HID + t], a3);
    bufB[t] = a3;
    __syncthreads();

    float o1 = rb1[t];
    for (int k = 0; k < HID; ++k) o1 = fmaf(bufB[k], rw1[k * HID + t], o1);
    o1 = fmaxf(o1, 0.f);
    bufA[t] = o1;
    __syncthreads();

    float o2 = rb2[t];
    for (int k = 0; k < HID; ++k) o2 = fmaf(bufA[k], rw2[k * HID + t], o2);
    o2 = fmaxf(o2, 0.f);
    bufB[t] = o2;
    __syncthreads();

    if (t < DOUT) {
        float o3 = rb3[t];
        for (int k = 0; k < HID; ++k) o3 = fmaf(bufB[k], rw3[k * DOUT + t], o3);
        out[b * DOUT + t] = (cnt > 0) ? o3 : 0.f;
    }
}
} // namespace

extern "C" void kernel_launch(void* const* d_in, const int* in_sizes, int n_in,
                              void* d_out, int out_size, void* d_ws, size_t ws_size,
                              hipStream_t stream) {
    const float* x    = (const float*)d_in[0];
    const int*   mask = (const int*)  d_in[1];
    const float* pw1  = (const float*)d_in[2];
    const float* pb1  = (const float*)d_in[3];
    const float* pw2  = (const float*)d_in[4];
    const float* pb2  = (const float*)d_in[5];
    const float* pw3  = (const float*)d_in[6];
    const float* pb3  = (const float*)d_in[7];
    const float* rw1  = (const float*)d_in[8];
    const float* rb1  = (const float*)d_in[9];
    const float* rw2  = (const float*)d_in[10];
    const float* rb2  = (const float*)d_in[11];
    const float* rw3  = (const float*)d_in[12];
    const float* rb3  = (const float*)d_in[13];
    float* out = (float*)d_out;

    float* pooled        = (float*)((char*)d_ws + POOLED_OFF);
    unsigned short* w1p  = (unsigned short*)((char*)d_ws + PW1_OFF);
    unsigned short* w2p  = (unsigned short*)((char*)d_ws + PW2_OFF);

    prep<<<dim3(256), dim3(256), 0, stream>>>(pw1, pw2, pooled, w1p, w2p);
    phi_pool<<<dim3(NB, SPLIT), dim3(256), 0, stream>>>(x, mask, pb1, pb2, w1p, w2p, pooled);
    rho<<<dim3(NB), dim3(256), 0, stream>>>(pooled, mask, pw3, pb3,
                                            rw1, rb1, rw2, rb2, rw3, rb3, out);
}